// Round 16
// baseline (447.846 us; speedup 1.0000x reference)
//
#include <hip/hip_runtime.h>
#include <hip/hip_bf16.h>
#include <stdint.h>

// out = x @ W'^T + bias, W' = FWHT(W rows)/sqrt(n)  (H symmetric, folded into W)
// x (4,2048,8192) f32 -> M=8192, K=8192 ; W (2048,8192) -> N=2048 ; out f32.
// R16: cvt_x kernel ELIMINATED -- gemm reads A as f32 and converts during
// reg-staging (load f32 -> cvt -> ds_write). Saves the 402MB xb round trip.

#define M_TOTAL 8192
#define K_TOTAL 8192
#define N_TOTAL 2048
#define D_IN 8192

typedef __attribute__((ext_vector_type(8))) short short8;
typedef __attribute__((ext_vector_type(4))) float f32x4;

typedef __attribute__((address_space(1))) void void_g;
typedef __attribute__((address_space(3))) void void_l;
typedef __attribute__((address_space(3))) short lds_s3;

__device__ __forceinline__ short f2bf(float f) {
  __hip_bfloat16 h = __float2bfloat16(f);
  return *reinterpret_cast<short*>(&h);
}

__device__ __forceinline__ short8 cvt8(float4 a, float4 b) {
  short8 s;
  s[0] = f2bf(a.x); s[1] = f2bf(a.y); s[2] = f2bf(a.z); s[3] = f2bf(a.w);
  s[4] = f2bf(b.x); s[5] = f2bf(b.y); s[6] = f2bf(b.z); s[7] = f2bf(b.w);
  return s;
}

// ---------------- kernel 1: W' = FWHT(W rows) / sqrt(n), bf16 ----------------
__global__ void fwht_w_kernel(const float* __restrict__ W, short* __restrict__ Wh) {
  __shared__ float buf[D_IN];
  const int row = blockIdx.x;
  const float* src = W + (long)row * D_IN;
  for (int i = threadIdx.x; i < D_IN / 4; i += blockDim.x)
    ((float4*)buf)[i] = ((const float4*)src)[i];
  for (int h = 1; h < D_IN; h <<= 1) {
    __syncthreads();
    for (int p = threadIdx.x; p < D_IN / 2; p += blockDim.x) {
      int i = ((p & ~(h - 1)) << 1) | (p & (h - 1));
      float a = buf[i], b = buf[i + h];
      buf[i] = a + b;
      buf[i + h] = a - b;
    }
  }
  __syncthreads();
  const float s = 0.011048543456039806f; // 1/sqrt(8192)
  short* dst = Wh + (long)row * D_IN;
  for (int i = threadIdx.x; i < D_IN; i += blockDim.x)
    dst[i] = f2bf(buf[i] * s);
}

// ---------------- kernel 2: 256x256 8-phase GEMM, f32-A in-staging convert ------
// R14's schedule/layout (BK=64, 2-dbuf, per-phase barriers, coalesced XOR-
// swizzled LDS: chunk c of row r at slot c^(r&7)), except A is staged from f32:
//   ph1: issue 4 float4 loads (A(t+next) half0)   [compiler-visible, SBAR-pinned]
//   ph2: issue 4 float4 loads (half1)
//   ph3: cvt half0 -> 2 asm ds_write_b128 ; 2 gld_lds (B)
//   ph4: cvt half1 -> 2 asm ds_write_b128 ; 2 gld_lds (B); lgkm(0)+barrier
// Compiler inserts precise counted vmcnt before each cvt use; B's gld_lds are
// OLDER in the per-wave VMEM FIFO so they drain with it -> no manual vmcnt
// fences needed in the main loop. ds_writes retired by lgkm(0) before the end
// barrier. LDS write traffic identical to DMA staging (same bytes).
#define NT 128 // K-tiles of 64

#define BDST(D, H) (32768 + ((D) * 2 + (H)) * 8192 + sdst)  // shorts

#define STG(DST, SRC, KOFF)                                                                       \
  __builtin_amdgcn_global_load_lds((void_g*)((SRC) + (KOFF)), (void_l*)&lds[DST], 16, 0, 0);      \
  __builtin_amdgcn_global_load_lds((void_g*)((SRC) + (KOFF) + 64 * (long)K_TOTAL),                \
                                   (void_l*)&lds[(DST) + 4096], 16, 0, 0);

#define DSR(dst, ADDR, IMM)                                                                       \
  asm volatile("ds_read_b128 %0, %1 offset:%2" : "=v"(dst) : "v"(ADDR), "i"(IMM))

// A write: base awA (tid*16 within A region), imm = (D*2+H)*16384 (+8192 for +64 rows)
#define AWR(D, H, SA, SB)                                                                         \
  asm volatile("ds_write_b128 %0, %1 offset:%2" ::"v"(awA), "v"(SA),                              \
               "i"(((D) * 2 + (H)) * 16384) : "memory");                                          \
  asm volatile("ds_write_b128 %0, %1 offset:%2" ::"v"(awA), "v"(SB),                              \
               "i"(((D) * 2 + (H)) * 16384 + 8192) : "memory");

#define RD_A4(D, MIB)                                                                             \
  DSR(am[0][0], aAd0, (D) * 32768 + ((MIB) + 0) * 2048);                                          \
  DSR(am[0][1], aAd1, (D) * 32768 + ((MIB) + 0) * 2048);                                          \
  DSR(am[1][0], aAd0, (D) * 32768 + ((MIB) + 1) * 2048);                                          \
  DSR(am[1][1], aAd1, (D) * 32768 + ((MIB) + 1) * 2048);                                          \
  DSR(am[2][0], aAd0, (D) * 32768 + ((MIB) + 2) * 2048);                                          \
  DSR(am[2][1], aAd1, (D) * 32768 + ((MIB) + 2) * 2048);                                          \
  DSR(am[3][0], aAd0, (D) * 32768 + ((MIB) + 3) * 2048);                                          \
  DSR(am[3][1], aAd1, (D) * 32768 + ((MIB) + 3) * 2048);

#define RD_B2(D, NJB)                                                                             \
  DSR(bn[(NJB) + 0][0], bAd0, (D) * 32768 + ((NJB) + 0) * 2048);                                  \
  DSR(bn[(NJB) + 0][1], bAd1, (D) * 32768 + ((NJB) + 0) * 2048);                                  \
  DSR(bn[(NJB) + 1][0], bAd0, (D) * 32768 + ((NJB) + 1) * 2048);                                  \
  DSR(bn[(NJB) + 1][1], bAd1, (D) * 32768 + ((NJB) + 1) * 2048);

#define MF(MIB, NJB)                                                                              \
  __builtin_amdgcn_s_setprio(1);                                                                  \
  _Pragma("unroll") for (int mi = 0; mi < 4; ++mi) {                                              \
    _Pragma("unroll") for (int nj = 0; nj < 2; ++nj) {                                            \
      _Pragma("unroll") for (int ks = 0; ks < 2; ++ks) acc[(MIB) + mi][(NJB) + nj] =              \
          __builtin_amdgcn_mfma_f32_16x16x32_bf16(am[mi][ks], bn[(NJB) + nj][ks],                 \
                                                  acc[(MIB) + mi][(NJB) + nj], 0, 0, 0);          \
    }                                                                                             \
  }                                                                                               \
  __builtin_amdgcn_s_setprio(0);

#define BAR __builtin_amdgcn_s_barrier()
#define SBAR __builtin_amdgcn_sched_barrier(0)
#define LG0 do { asm volatile("s_waitcnt lgkmcnt(0)"); SBAR; } while (0)

// one K-tile. STGA: stage A(next) into dbuf D^1 (f32 loads ph1/2, writes ph3/4).
// STGB: stage B at KB via gld_lds. LB: trailing barrier.
#define KTILE(D, STGA, KA, STGB, KB, LB)                                                          \
  {                                                                                               \
    RD_B2(D, 0);                                                                                  \
    RD_A4(D, 0);                                                                                  \
    if (STGA) {                                                                                   \
      a00 = *(const float4*)(aF0 + (KA));                                                         \
      a01 = *(const float4*)(aF0 + (KA) + 4);                                                     \
      a02 = *(const float4*)(aF1 + (KA));                                                         \
      a03 = *(const float4*)(aF1 + (KA) + 4);                                                     \
    }                                                                                             \
    asm volatile("s_waitcnt lgkmcnt(8)");                                                         \
    BAR;                                                                                          \
    LG0;                                                                                          \
    MF(0, 0);                                                                                     \
    BAR;                                                                                          \
    RD_B2(D, 2);                                                                                  \
    if (STGA) {                                                                                   \
      a10 = *(const float4*)(aF2 + (KA));                                                         \
      a11 = *(const float4*)(aF2 + (KA) + 4);                                                     \
      a12 = *(const float4*)(aF3 + (KA));                                                         \
      a13 = *(const float4*)(aF3 + (KA) + 4);                                                     \
    }                                                                                             \
    BAR;                                                                                          \
    LG0;                                                                                          \
    MF(0, 2);                                                                                     \
    BAR;                                                                                          \
    RD_A4(D, 4);                                                                                  \
    if (STGA) { AWR(D ^ 1, 0, cvt8(a00, a01), cvt8(a02, a03)); }                                  \
    if (STGB) { STG(BDST(D, 0), bSrc0, KB); }                                                     \
    BAR;                                                                                          \
    LG0;                                                                                          \
    MF(4, 0);                                                                                     \
    BAR;                                                                                          \
    if (STGA) { AWR(D ^ 1, 1, cvt8(a10, a11), cvt8(a12, a13)); }                                  \
    if (STGB) { STG(BDST(D, 1), bSrc1, KB); }                                                     \
    BAR;                                                                                          \
    MF(4, 2);                                                                                     \
    asm volatile("s_waitcnt lgkmcnt(0)");                                                         \
    if (LB) BAR;                                                                                  \
  }

__global__ __launch_bounds__(512, 2) void gemm_kernel(const float* __restrict__ X,
                                                      const short* __restrict__ B,
                                                      const float* __restrict__ bias,
                                                      float* __restrict__ C) {
  __shared__ __attribute__((aligned(16))) short lds[65536]; // 128 KiB

  const int tid = threadIdx.x;
  const int l = tid & 63;
  const int w = tid >> 6;
  const int wm = w >> 2;   // 0..1 (M half)
  const int wn = w & 3;    // 0..3 (N quarter)
  const int wh = wn >> 1;  // B half

  // XCD-aware bijective swizzle (nwg = 256)
  const int bid = blockIdx.x;
  const int swz = (bid & 7) * 32 + (bid >> 3);
  const int bm = swz >> 3;
  const int bn_ = swz & 7;
  const long tileM = (long)bm * 256;
  const long tileN = (long)bn_ * 256;

  // read bases (bytes): row-in-frag = l&15, slot0 = (l>>4) ^ (l&7); ks1 = ^64
  const int slot0 = (l >> 4) ^ (l & 7);
  const int laneb = (l & 15) * 128 + slot0 * 16;
  const unsigned ldsb = (unsigned)(uintptr_t)(lds_s3*)&lds[0];
  const unsigned aAd0 = ldsb + (unsigned)(wm * 16384 + laneb);
  const unsigned aAd1 = aAd0 ^ 64u;
  const unsigned bAd0 = ldsb + 65536u + (unsigned)(wh * 16384 + (wn & 1) * 8192 + laneb);
  const unsigned bAd1 = bAd0 ^ 64u;

  // staging geometry: thread t -> LDS chunk t (row t>>3, slot t&7); source
  // chunk (t&7)^((t>>3)&7). A from f32 x; B from bf16 W'.
  const int sdst = tid * 8;                        // shorts (B staging dest)
  const int srow = tid >> 3;                       // 0..63
  const int scol = ((tid & 7) ^ (srow & 7)) * 8;   // element offset
  const float* aF0 = X + (tileM + srow) * (long)K_TOTAL + scol;          // rows 0-63
  const float* aF1 = aF0 + 64 * (long)K_TOTAL;                           // rows 64-127
  const float* aF2 = aF0 + 128 * (long)K_TOTAL;                          // rows 128-191
  const float* aF3 = aF0 + 192 * (long)K_TOTAL;                          // rows 192-255
  const short* bSrc0 = B + (tileN + srow) * (long)K_TOTAL + scol;
  const short* bSrc1 = bSrc0 + 128 * (long)K_TOTAL;
  const unsigned awA = ldsb + (unsigned)tid * 16u; // A-region write base (bytes)

  f32x4 acc[8][4];
#pragma unroll
  for (int mi = 0; mi < 8; ++mi)
#pragma unroll
    for (int nj = 0; nj < 4; ++nj)
      acc[mi][nj] = (f32x4){0.f, 0.f, 0.f, 0.f};

  float4 a00, a01, a02, a03, a10, a11, a12, a13;

  // prologue: A(0)->d0 via load+cvt+write; B(0)->d0, B(1)->d1 via gld_lds
  a00 = *(const float4*)(aF0);
  a01 = *(const float4*)(aF0 + 4);
  a02 = *(const float4*)(aF1);
  a03 = *(const float4*)(aF1 + 4);
  a10 = *(const float4*)(aF2);
  a11 = *(const float4*)(aF2 + 4);
  a12 = *(const float4*)(aF3);
  a13 = *(const float4*)(aF3 + 4);
  STG(BDST(0, 0), bSrc0, 0);
  STG(BDST(0, 1), bSrc1, 0);
  STG(BDST(1, 0), bSrc0, 64);
  STG(BDST(1, 1), bSrc1, 64);
  AWR(0, 0, cvt8(a00, a01), cvt8(a02, a03)); // compiler waits its f32 loads
  AWR(0, 1, cvt8(a10, a11), cvt8(a12, a13));
  asm volatile("s_waitcnt vmcnt(0)");
  asm volatile("s_waitcnt lgkmcnt(0)");
  BAR;

  short8 am[4][2], bn[4][2];

  // main: t = 0,2,...,124; even tile stages A(t+1)->d1, B(t+2)->d0;
  // odd tile stages A(t+2)->d0, B(t+3)->d1
  for (int t = 0; t < NT - 2; t += 2) {
    KTILE(0, true, (t + 1) * 64, true, (t + 2) * 64, true);
    KTILE(1, true, (t + 2) * 64, true, (t + 3) * 64, true);
  }
  // tail: t=126 stages A(127)->d1 only; t=127 compute-only
  KTILE(0, true, 127 * 64, false, 0, true);
  KTILE(1, false, 0, false, 0, false);

  // epilogue: C = acc + bias  (C/D map: col = l&15, row = (l>>4)*4 + reg)
  const int rb = (int)tileM + wm * 128 + (l >> 4) * 4;
  const int cb = (int)tileN + wn * 64 + (l & 15);
#pragma unroll
  for (int mi = 0; mi < 8; ++mi)
#pragma unroll
    for (int nj = 0; nj < 4; ++nj) {
      float bv = bias[cb + nj * 16];
      const int r0 = rb + mi * 16;
#pragma unroll
      for (int r = 0; r < 4; ++r)
        C[(long)(r0 + r) * N_TOTAL + cb + nj * 16] = acc[mi][nj][r] + bv;
    }
}

extern "C" void kernel_launch(void* const* d_in, const int* in_sizes, int n_in,
                              void* d_out, int out_size, void* d_ws, size_t ws_size,
                              hipStream_t stream) {
  const float* x = (const float*)d_in[0];
  const float* W = (const float*)d_in[1];
  const float* bias = (const float*)d_in[2];
  float* out = (float*)d_out;

  short* wh = (short*)d_ws; // 2048*8192*2 = 33.5 MB

  fwht_w_kernel<<<N_TOTAL, 256, 0, stream>>>(W, wh);

  const int grid = (M_TOTAL / 256) * (N_TOTAL / 256); // 256
  gemm_kernel<<<grid, 512, 0, stream>>>(x, wh, bias, out);
}

// Round 17
// 433.310 us; speedup vs baseline: 1.0335x; 1.0335x over previous
//
#include <hip/hip_runtime.h>
#include <hip/hip_bf16.h>
#include <stdint.h>

// out = x @ W'^T + bias, W' = FWHT(W rows)/sqrt(n)  (H symmetric, folded into W)
// x (4,2048,8192) f32 -> M=8192, K=8192 ; W (2048,8192) -> N=2048 ; out f32.
// R17: in-gemm A conversion, corrected: (1) ds_write asm WITHOUT "memory"
// clobber (R16's clobber made the waitcnt pass insert vmcnt(0) before every
// AWR, draining B's pipeline twice per tile -> 26% MfmaUtil); (2) A f32 loads
// issued at t.ph4, consumed at (t+1).ph3 (~2150 cy slack vs R16's ~1100).

#define M_TOTAL 8192
#define K_TOTAL 8192
#define N_TOTAL 2048
#define D_IN 8192

typedef __attribute__((ext_vector_type(8))) short short8;
typedef __attribute__((ext_vector_type(4))) float f32x4;

typedef __attribute__((address_space(1))) void void_g;
typedef __attribute__((address_space(3))) void void_l;
typedef __attribute__((address_space(3))) short lds_s3;

__device__ __forceinline__ short f2bf(float f) {
  __hip_bfloat16 h = __float2bfloat16(f);
  return *reinterpret_cast<short*>(&h);
}

__device__ __forceinline__ short8 cvt8(float4 a, float4 b) {
  short8 s;
  s[0] = f2bf(a.x); s[1] = f2bf(a.y); s[2] = f2bf(a.z); s[3] = f2bf(a.w);
  s[4] = f2bf(b.x); s[5] = f2bf(b.y); s[6] = f2bf(b.z); s[7] = f2bf(b.w);
  return s;
}

// ---------------- kernel 1: W' = FWHT(W rows) / sqrt(n), bf16 ----------------
__global__ void fwht_w_kernel(const float* __restrict__ W, short* __restrict__ Wh) {
  __shared__ float buf[D_IN];
  const int row = blockIdx.x;
  const float* src = W + (long)row * D_IN;
  for (int i = threadIdx.x; i < D_IN / 4; i += blockDim.x)
    ((float4*)buf)[i] = ((const float4*)src)[i];
  for (int h = 1; h < D_IN; h <<= 1) {
    __syncthreads();
    for (int p = threadIdx.x; p < D_IN / 2; p += blockDim.x) {
      int i = ((p & ~(h - 1)) << 1) | (p & (h - 1));
      float a = buf[i], b = buf[i + h];
      buf[i] = a + b;
      buf[i + h] = a - b;
    }
  }
  __syncthreads();
  const float s = 0.011048543456039806f; // 1/sqrt(8192)
  short* dst = Wh + (long)row * D_IN;
  for (int i = threadIdx.x; i < D_IN; i += blockDim.x)
    dst[i] = f2bf(buf[i] * s);
}

// ---------------- kernel 2: 256x256 8-phase GEMM, f32-A converted in staging ----
// Schedule/layout = R14 (BK=64, 2-dbuf, per-phase barriers, coalesced XOR-
// swizzled LDS: chunk c of row r at slot c^(r&7); 0 bank conflicts). A staging:
//   t.ph3: AWR half0 (cvt aR[0..3] -> 2 asm ds_write_b128, no clobber)
//   t.ph4: AWR half1 (cvt aR[4..7]); THEN issue 8 float4 loads of A(t+2) -> aR
// B staging: gld_lds as before (B(t+2) at t.ph3/ph4). Validity ledger:
//  - A(t+1) LDS-visible at t+1: ds_writes drained by t's lgkm(0), then barrier.
//  - B(t+2): its 4 gld_lds (t.ph3/ph4) are OLDER than aR loads (end of t.ph4);
//    the compiler's counted vmcnt wait before the cvt at (t+1).ph3 covers them;
//    end-of-(t+1) barrier publishes -> reads at t+2 safe. No manual vmcnt.
//  - aR register WAR: AWR reads aR at issue (t.ph3/ph4) before the loads
//    redefine them (program order within thread).
#define NT 128 // K-tiles of 64

#define BDST(D, H) (32768 + ((D) * 2 + (H)) * 8192 + sdst)  // shorts

#define STG(DST, SRC, KOFF)                                                                       \
  __builtin_amdgcn_global_load_lds((void_g*)((SRC) + (KOFF)), (void_l*)&lds[DST], 16, 0, 0);      \
  __builtin_amdgcn_global_load_lds((void_g*)((SRC) + (KOFF) + 64 * (long)K_TOTAL),                \
                                   (void_l*)&lds[(DST) + 4096], 16, 0, 0);

#define DSR(dst, ADDR, IMM)                                                                       \
  asm volatile("ds_read_b128 %0, %1 offset:%2" : "=v"(dst) : "v"(ADDR), "i"(IMM))

// A write: base awA (tid*16 in A region), imm = (D*2+H)*16384 (+8192 = rows+64).
// NOTE: no "memory" clobber (see header comment).
#define AWR(D, H, SA, SB)                                                                         \
  asm volatile("ds_write_b128 %0, %1 offset:%2" ::"v"(awA), "v"(SA),                              \
               "i"(((D) * 2 + (H)) * 16384));                                                     \
  asm volatile("ds_write_b128 %0, %1 offset:%2" ::"v"(awA), "v"(SB),                              \
               "i"(((D) * 2 + (H)) * 16384 + 8192));

#define RD_A4(D, MIB)                                                                             \
  DSR(am[0][0], aAd0, (D) * 32768 + ((MIB) + 0) * 2048);                                          \
  DSR(am[0][1], aAd1, (D) * 32768 + ((MIB) + 0) * 2048);                                          \
  DSR(am[1][0], aAd0, (D) * 32768 + ((MIB) + 1) * 2048);                                          \
  DSR(am[1][1], aAd1, (D) * 32768 + ((MIB) + 1) * 2048);                                          \
  DSR(am[2][0], aAd0, (D) * 32768 + ((MIB) + 2) * 2048);                                          \
  DSR(am[2][1], aAd1, (D) * 32768 + ((MIB) + 2) * 2048);                                          \
  DSR(am[3][0], aAd0, (D) * 32768 + ((MIB) + 3) * 2048);                                          \
  DSR(am[3][1], aAd1, (D) * 32768 + ((MIB) + 3) * 2048);

#define RD_B2(D, NJB)                                                                             \
  DSR(bn[(NJB) + 0][0], bAd0, (D) * 32768 + ((NJB) + 0) * 2048);                                  \
  DSR(bn[(NJB) + 0][1], bAd1, (D) * 32768 + ((NJB) + 0) * 2048);                                  \
  DSR(bn[(NJB) + 1][0], bAd0, (D) * 32768 + ((NJB) + 1) * 2048);                                  \
  DSR(bn[(NJB) + 1][1], bAd1, (D) * 32768 + ((NJB) + 1) * 2048);

#define MF(MIB, NJB)                                                                              \
  __builtin_amdgcn_s_setprio(1);                                                                  \
  _Pragma("unroll") for (int mi = 0; mi < 4; ++mi) {                                              \
    _Pragma("unroll") for (int nj = 0; nj < 2; ++nj) {                                            \
      _Pragma("unroll") for (int ks = 0; ks < 2; ++ks) acc[(MIB) + mi][(NJB) + nj] =              \
          __builtin_amdgcn_mfma_f32_16x16x32_bf16(am[mi][ks], bn[(NJB) + nj][ks],                 \
                                                  acc[(MIB) + mi][(NJB) + nj], 0, 0, 0);          \
    }                                                                                             \
  }                                                                                               \
  __builtin_amdgcn_s_setprio(0);

#define BAR __builtin_amdgcn_s_barrier()
#define SBAR __builtin_amdgcn_sched_barrier(0)
#define LG0 do { asm volatile("s_waitcnt lgkmcnt(0)"); SBAR; } while (0)

#define LD_A8(KA2)                                                                                \
  aR0 = *(const float4*)(aF0 + (KA2));                                                            \
  aR1 = *(const float4*)(aF0 + (KA2) + 4);                                                        \
  aR2 = *(const float4*)(aF1 + (KA2));                                                            \
  aR3 = *(const float4*)(aF1 + (KA2) + 4);                                                        \
  aR4 = *(const float4*)(aF2 + (KA2));                                                            \
  aR5 = *(const float4*)(aF2 + (KA2) + 4);                                                        \
  aR6 = *(const float4*)(aF3 + (KA2));                                                            \
  aR7 = *(const float4*)(aF3 + (KA2) + 4);

// one K-tile. STGA: write A(t+1) (from aR) into dbuf D^1. STGB: stage B at KB.
// LDN: issue A(t+2) f32 loads at KA2. LB: trailing barrier.
#define KTILE(D, STGA, STGB, KB, LDN, KA2, LB)                                                    \
  {                                                                                               \
    RD_B2(D, 0);                                                                                  \
    RD_A4(D, 0);                                                                                  \
    asm volatile("s_waitcnt lgkmcnt(8)");                                                         \
    BAR;                                                                                          \
    LG0;                                                                                          \
    MF(0, 0);                                                                                     \
    BAR;                                                                                          \
    RD_B2(D, 2);                                                                                  \
    BAR;                                                                                          \
    LG0;                                                                                          \
    MF(0, 2);                                                                                     \
    BAR;                                                                                          \
    RD_A4(D, 4);                                                                                  \
    if (STGB) { STG(BDST(D, 0), bSrc0, KB); }                                                     \
    if (STGA) { AWR(D ^ 1, 0, cvt8(aR0, aR1), cvt8(aR2, aR3)); }                                  \
    BAR;                                                                                          \
    LG0;                                                                                          \
    MF(4, 0);                                                                                     \
    BAR;                                                                                          \
    if (STGB) { STG(BDST(D, 1), bSrc1, KB); }                                                     \
    if (STGA) { AWR(D ^ 1, 1, cvt8(aR4, aR5), cvt8(aR6, aR7)); }                                  \
    if (LDN) { LD_A8(KA2); }                                                                      \
    BAR;                                                                                          \
    MF(4, 2);                                                                                     \
    asm volatile("s_waitcnt lgkmcnt(0)");                                                         \
    if (LB) BAR;                                                                                  \
  }

__global__ __launch_bounds__(512, 2) void gemm_kernel(const float* __restrict__ X,
                                                      const short* __restrict__ B,
                                                      const float* __restrict__ bias,
                                                      float* __restrict__ C) {
  __shared__ __attribute__((aligned(16))) short lds[65536]; // 128 KiB

  const int tid = threadIdx.x;
  const int l = tid & 63;
  const int w = tid >> 6;
  const int wm = w >> 2;   // 0..1 (M half)
  const int wn = w & 3;    // 0..3 (N quarter)
  const int wh = wn >> 1;  // B half

  // XCD-aware bijective swizzle (nwg = 256)
  const int bid = blockIdx.x;
  const int swz = (bid & 7) * 32 + (bid >> 3);
  const int bm = swz >> 3;
  const int bn_ = swz & 7;
  const long tileM = (long)bm * 256;
  const long tileN = (long)bn_ * 256;

  // read bases (bytes): row-in-frag = l&15, slot0 = (l>>4) ^ (l&7); ks1 = ^64
  const int slot0 = (l >> 4) ^ (l & 7);
  const int laneb = (l & 15) * 128 + slot0 * 16;
  const unsigned ldsb = (unsigned)(uintptr_t)(lds_s3*)&lds[0];
  const unsigned aAd0 = ldsb + (unsigned)(wm * 16384 + laneb);
  const unsigned aAd1 = aAd0 ^ 64u;
  const unsigned bAd0 = ldsb + 65536u + (unsigned)(wh * 16384 + (wn & 1) * 8192 + laneb);
  const unsigned bAd1 = bAd0 ^ 64u;

  // staging geometry: thread t -> LDS chunk t (row t>>3, slot t&7); source
  // chunk (t&7)^((t>>3)&7). A from f32 X; B from bf16 W'.
  const int sdst = tid * 8;                        // shorts (B staging dest)
  const int srow = tid >> 3;                       // 0..63
  const int scol = ((tid & 7) ^ (srow & 7)) * 8;   // element offset
  const float* aF0 = X + (tileM + srow) * (long)K_TOTAL + scol;   // rows 0-63
  const float* aF1 = aF0 + 64 * (long)K_TOTAL;                    // rows 64-127
  const float* aF2 = aF0 + 128 * (long)K_TOTAL;                   // rows 128-191
  const float* aF3 = aF0 + 192 * (long)K_TOTAL;                   // rows 192-255
  const short* bSrc0 = B + (tileN + srow) * (long)K_TOTAL + scol;
  const short* bSrc1 = bSrc0 + 128 * (long)K_TOTAL;
  const unsigned awA = ldsb + (unsigned)tid * 16u; // A-region write base (bytes)

  f32x4 acc[8][4];
#pragma unroll
  for (int mi = 0; mi < 8; ++mi)
#pragma unroll
    for (int nj = 0; nj < 4; ++nj)
      acc[mi][nj] = (f32x4){0.f, 0.f, 0.f, 0.f};

  float4 aR0, aR1, aR2, aR3, aR4, aR5, aR6, aR7;

  // prologue: A(0) load+cvt+write -> d0; B(0)->d0, B(1)->d1; A(1) loads -> aR.
  LD_A8(0);
  STG(BDST(0, 0), bSrc0, 0);
  STG(BDST(0, 1), bSrc1, 0);
  STG(BDST(1, 0), bSrc0, 64);
  STG(BDST(1, 1), bSrc1, 64);
  AWR(0, 0, cvt8(aR0, aR1), cvt8(aR2, aR3)); // compiler waits the f32 loads
  AWR(0, 1, cvt8(aR4, aR5), cvt8(aR6, aR7));
  LD_A8(64); // A(1) into aR
  asm volatile("s_waitcnt vmcnt(8)"); // drains B(0),B(1); leaves the 8 A(1) loads
  asm volatile("s_waitcnt lgkmcnt(0)");
  BAR;

  short8 am[4][2], bn[4][2];

  // main: tiles 0..125. Tile t: write A(t+1)->d(D^1); stage B(t+2)->d(D);
  // load A(t+2)->aR.
  for (int t = 0; t < NT - 2; t += 2) {
    KTILE(0, true, true, (t + 2) * 64, true, (t + 2) * 64, true);
    KTILE(1, true, true, (t + 3) * 64, true, (t + 3) * 64, true);
  }
  // tile 126: write A(127)->d1 (aR loaded at 125); no B, no loads
  KTILE(0, true, false, 0, false, 0, true);
  // tile 127: compute only
  KTILE(1, false, false, 0, false, 0, false);

  // epilogue: C = acc + bias  (C/D map: col = l&15, row = (l>>4)*4 + reg)
  const int rb = (int)tileM + wm * 128 + (l >> 4) * 4;
  const int cb = (int)tileN + wn * 64 + (l & 15);
#pragma unroll
  for (int mi = 0; mi < 8; ++mi)
#pragma unroll
    for (int nj = 0; nj < 4; ++nj) {
      float bv = bias[cb + nj * 16];
      const int r0 = rb + mi * 16;
#pragma unroll
      for (int r = 0; r < 4; ++r)
        C[(long)(r0 + r) * N_TOTAL + cb + nj * 16] = acc[mi][nj][r] + bv;
    }
}

extern "C" void kernel_launch(void* const* d_in, const int* in_sizes, int n_in,
                              void* d_out, int out_size, void* d_ws, size_t ws_size,
                              hipStream_t stream) {
  const float* x = (const float*)d_in[0];
  const float* W = (const float*)d_in[1];
  const float* bias = (const float*)d_in[2];
  float* out = (float*)d_out;

  short* wh = (short*)d_ws; // 2048*8192*2 = 33.5 MB

  fwht_w_kernel<<<N_TOTAL, 256, 0, stream>>>(W, wh);

  const int grid = (M_TOTAL / 256) * (N_TOTAL / 256); // 256
  gemm_kernel<<<grid, 512, 0, stream>>>(x, wh, bias, out);
}

// Round 18
// 316.065 us; speedup vs baseline: 1.4169x; 1.3709x over previous
//
#include <hip/hip_runtime.h>
#include <hip/hip_bf16.h>
#include <stdint.h>

// out = x @ W'^T + bias, W' = FWHT(W rows)/sqrt(n)  (H symmetric, folded into W)
// x (4,2048,8192) f32 -> M=8192, K=8192 ; W (2048,8192) -> N=2048 ; out f32.
// R18: revert to R15 config (materialized bf16 A; in-gemm cvt failed twice at
// ~26% MfmaUtil -- compiler's FIFO-position wait for the f32 A-loads forces
// vmcnt(0), draining B staging). Prep split changed bid<2048 -> parity so cvt
// (HBM-bound) and fwht (LDS-bound) blocks co-reside per CU from t=0 (the old
// split dispatched ~all cvt first at 5 blocks/CU occupancy, serializing fwht).

#define M_TOTAL 8192
#define K_TOTAL 8192
#define N_TOTAL 2048
#define D_IN 8192

typedef __attribute__((ext_vector_type(8))) short short8;
typedef __attribute__((ext_vector_type(4))) float f32x4;

typedef __attribute__((address_space(1))) void void_g;
typedef __attribute__((address_space(3))) void void_l;
typedef __attribute__((address_space(3))) short lds_s3;

__device__ __forceinline__ short f2bf(float f) {
  __hip_bfloat16 h = __float2bfloat16(f);
  return *reinterpret_cast<short*>(&h);
}

// ---------------- kernel 1: fused prep (cvt_x || fwht_w, parity-interleaved) ----
__global__ __launch_bounds__(256) void prep_kernel(const float* __restrict__ x,
                                                   short* __restrict__ xb,
                                                   const float* __restrict__ W,
                                                   short* __restrict__ wh) {
  __shared__ float buf[D_IN];
  const int b = blockIdx.x;
  if ((b & 1) == 0) {
    // ---- cvt path (blocks 0,2,...,8190 -> 2048 workers) ----
    const int cb = b >> 1;
    const long n = (long)M_TOTAL * K_TOTAL;
    const long stride = (long)2048 * 256 * 8;
    for (long i = ((long)cb * 256 + threadIdx.x) * 8; i < n; i += stride) {
      float4 v0 = *(const float4*)(x + i);
      float4 v1 = *(const float4*)(x + i + 4);
      short8 o;
      o[0] = f2bf(v0.x); o[1] = f2bf(v0.y); o[2] = f2bf(v0.z); o[3] = f2bf(v0.w);
      o[4] = f2bf(v1.x); o[5] = f2bf(v1.y); o[6] = f2bf(v1.z); o[7] = f2bf(v1.w);
      *(short8*)(xb + i) = o;
    }
  } else {
    // ---- fwht path (blocks 1,3,...,4095 -> 2048 rows) ----
    const int row = b >> 1;
    const float* src = W + (long)row * D_IN;
    for (int i = threadIdx.x; i < D_IN / 4; i += blockDim.x)
      ((float4*)buf)[i] = ((const float4*)src)[i];
    for (int h = 1; h < D_IN; h <<= 1) {
      __syncthreads();
      for (int p = threadIdx.x; p < D_IN / 2; p += blockDim.x) {
        int i = ((p & ~(h - 1)) << 1) | (p & (h - 1));
        float a = buf[i], bb = buf[i + h];
        buf[i] = a + bb;
        buf[i + h] = a - bb;
      }
    }
    __syncthreads();
    const float s = 0.011048543456039806f; // 1/sqrt(8192)
    short* dst = wh + (long)row * D_IN;
    for (int i = threadIdx.x; i < D_IN; i += blockDim.x)
      dst[i] = f2bf(buf[i] * s);
  }
}

// ---------------- kernel 2: 256x256 8-phase GEMM, coalesced XOR-swizzled LDS ----
// R14 gemm, UNCHANGED (230 us, 1196 TF, MfmaUtil 52.9%, 0 bank conflicts):
// 8-phase schedule (BK=64, 2-dbuf, per-phase barriers, vmcnt(4)/K-tile,
// lgkm(8) stagger) with coalesced staging. Halves = [128 rows][64 k] bf16
// row-major, 16B-chunk XOR swizzle: chunk c of row r stored at slot c ^ (r&7).
#define NT 128 // K-tiles of 64

#define ADST(D, H) (((D) * 2 + (H)) * 8192 + sdst)          // shorts
#define BDST(D, H) (32768 + ((D) * 2 + (H)) * 8192 + sdst)  // shorts

#define STG(DST, SRC, KOFF)                                                                       \
  __builtin_amdgcn_global_load_lds((void_g*)((SRC) + (KOFF)), (void_l*)&lds[DST], 16, 0, 0);      \
  __builtin_amdgcn_global_load_lds((void_g*)((SRC) + (KOFF) + 64 * (long)K_TOTAL),                \
                                   (void_l*)&lds[(DST) + 4096], 16, 0, 0);

#define DSR(dst, ADDR, IMM)                                                                       \
  asm volatile("ds_read_b128 %0, %1 offset:%2" : "=v"(dst) : "v"(ADDR), "i"(IMM))

#define RD_A4(D, MIB)                                                                             \
  DSR(am[0][0], aAd0, (D) * 32768 + ((MIB) + 0) * 2048);                                          \
  DSR(am[0][1], aAd1, (D) * 32768 + ((MIB) + 0) * 2048);                                          \
  DSR(am[1][0], aAd0, (D) * 32768 + ((MIB) + 1) * 2048);                                          \
  DSR(am[1][1], aAd1, (D) * 32768 + ((MIB) + 1) * 2048);                                          \
  DSR(am[2][0], aAd0, (D) * 32768 + ((MIB) + 2) * 2048);                                          \
  DSR(am[2][1], aAd1, (D) * 32768 + ((MIB) + 2) * 2048);                                          \
  DSR(am[3][0], aAd0, (D) * 32768 + ((MIB) + 3) * 2048);                                          \
  DSR(am[3][1], aAd1, (D) * 32768 + ((MIB) + 3) * 2048);

#define RD_B2(D, NJB)                                                                             \
  DSR(bn[(NJB) + 0][0], bAd0, (D) * 32768 + ((NJB) + 0) * 2048);                                  \
  DSR(bn[(NJB) + 0][1], bAd1, (D) * 32768 + ((NJB) + 0) * 2048);                                  \
  DSR(bn[(NJB) + 1][0], bAd0, (D) * 32768 + ((NJB) + 1) * 2048);                                  \
  DSR(bn[(NJB) + 1][1], bAd1, (D) * 32768 + ((NJB) + 1) * 2048);

#define MF(MIB, NJB)                                                                              \
  __builtin_amdgcn_s_setprio(1);                                                                  \
  _Pragma("unroll") for (int mi = 0; mi < 4; ++mi) {                                              \
    _Pragma("unroll") for (int nj = 0; nj < 2; ++nj) {                                            \
      _Pragma("unroll") for (int ks = 0; ks < 2; ++ks) acc[(MIB) + mi][(NJB) + nj] =              \
          __builtin_amdgcn_mfma_f32_16x16x32_bf16(am[mi][ks], bn[(NJB) + nj][ks],                 \
                                                  acc[(MIB) + mi][(NJB) + nj], 0, 0, 0);          \
    }                                                                                             \
  }                                                                                               \
  __builtin_amdgcn_s_setprio(0);

#define BAR __builtin_amdgcn_s_barrier()
#define SBAR __builtin_amdgcn_sched_barrier(0)
#define LG0 do { asm volatile("s_waitcnt lgkmcnt(0)"); SBAR; } while (0)

#define KTILE(D, STGA, KA, STGB, KB, FN, DOF, LB)                                                 \
  {                                                                                               \
    RD_B2(D, 0);                                                                                  \
    RD_A4(D, 0);                                                                                  \
    if (STGA) { STG(ADST(D ^ 1, 0), aSrc0, KA); }                                                 \
    asm volatile("s_waitcnt lgkmcnt(8)");                                                         \
    BAR;                                                                                          \
    LG0;                                                                                          \
    MF(0, 0);                                                                                     \
    BAR;                                                                                          \
    RD_B2(D, 2);                                                                                  \
    if (STGA) { STG(ADST(D ^ 1, 1), aSrc1, KA); }                                                 \
    BAR;                                                                                          \
    LG0;                                                                                          \
    MF(0, 2);                                                                                     \
    BAR;                                                                                          \
    RD_A4(D, 4);                                                                                  \
    if (STGB) { STG(BDST(D, 0), bSrc0, KB); }                                                     \
    BAR;                                                                                          \
    LG0;                                                                                          \
    MF(4, 0);                                                                                     \
    BAR;                                                                                          \
    if (STGB) { STG(BDST(D, 1), bSrc1, KB); }                                                     \
    BAR;                                                                                          \
    MF(4, 2);                                                                                     \
    if (DOF) { asm volatile("s_waitcnt vmcnt(" FN ")"); }                                         \
    if (LB) BAR;                                                                                  \
  }

__global__ __launch_bounds__(512, 2) void gemm_kernel(const short* __restrict__ A,
                                                      const short* __restrict__ B,
                                                      const float* __restrict__ bias,
                                                      float* __restrict__ C) {
  __shared__ __attribute__((aligned(16))) short lds[65536]; // 128 KiB

  const int tid = threadIdx.x;
  const int l = tid & 63;
  const int w = tid >> 6;
  const int wm = w >> 2;   // 0..1 (M half)
  const int wn = w & 3;    // 0..3 (N quarter)
  const int wh = wn >> 1;  // B half

  // XCD-aware bijective swizzle (nwg = 256)
  const int bid = blockIdx.x;
  const int swz = (bid & 7) * 32 + (bid >> 3);
  const int bm = swz >> 3;
  const int bn_ = swz & 7;
  const long tileM = (long)bm * 256;
  const long tileN = (long)bn_ * 256;

  // read bases (bytes): row-in-frag = l&15, slot0 = (l>>4) ^ (l&7); ks1 = ^64
  const int slot0 = (l >> 4) ^ (l & 7);
  const int laneb = (l & 15) * 128 + slot0 * 16;
  const unsigned ldsb = (unsigned)(uintptr_t)(lds_s3*)&lds[0];
  const unsigned aAd0 = ldsb + (unsigned)(wm * 16384 + laneb);
  const unsigned aAd1 = aAd0 ^ 64u;
  const unsigned bAd0 = ldsb + 65536u + (unsigned)(wh * 16384 + (wn & 1) * 8192 + laneb);
  const unsigned bAd1 = bAd0 ^ 64u;

  // staging: thread t -> LDS chunk t (row t>>3, slot t&7); global source chunk
  // (t&7)^((t>>3)&7) of row t>>3 (and +64 rows for the second load)
  const int sdst = tid * 8; // shorts
  const int srow = tid >> 3;
  const int sslot = ((tid & 7) ^ (srow & 7)) * 8; // shorts
  const short* aSrc0 = A + (tileM + srow) * (long)K_TOTAL + sslot;
  const short* aSrc1 = aSrc0 + 128 * (long)K_TOTAL;
  const short* bSrc0 = B + (tileN + srow) * (long)K_TOTAL + sslot;
  const short* bSrc1 = bSrc0 + 128 * (long)K_TOTAL;

  f32x4 acc[8][4];
#pragma unroll
  for (int mi = 0; mi < 8; ++mi)
#pragma unroll
    for (int nj = 0; nj < 4; ++nj)
      acc[mi][nj] = (f32x4){0.f, 0.f, 0.f, 0.f};

  // prologue: A(0)->d0, B(0)->d0, B(1)->d1 (12 loads); vmcnt(4) leaves B(1)
  STG(ADST(0, 0), aSrc0, 0);
  STG(ADST(0, 1), aSrc1, 0);
  STG(BDST(0, 0), bSrc0, 0);
  STG(BDST(0, 1), bSrc1, 0);
  STG(BDST(1, 0), bSrc0, 64);
  STG(BDST(1, 1), bSrc1, 64);
  asm volatile("s_waitcnt vmcnt(4)");
  BAR;

  short8 am[4][2], bn[4][2];

  // main: t = 0,2,...,124
  for (int t = 0; t < NT - 2; t += 2) {
    KTILE(0, true, (t + 1) * 64, true, (t + 2) * 64, "4", true, true);
    KTILE(1, true, (t + 2) * 64, true, (t + 3) * 64, "4", true, true);
  }
  // tail: t=126 stages A(127), drains; t=127 compute-only
  KTILE(0, true, 127 * 64, false, 0, "0", true, true);
  KTILE(1, false, 0, false, 0, "0", false, false);

  // epilogue: C = acc + bias  (C/D map: col = l&15, row = (l>>4)*4 + reg)
  const int rb = (int)tileM + wm * 128 + (l >> 4) * 4;
  const int cb = (int)tileN + wn * 64 + (l & 15);
#pragma unroll
  for (int mi = 0; mi < 8; ++mi)
#pragma unroll
    for (int nj = 0; nj < 4; ++nj) {
      float bv = bias[cb + nj * 16];
      const int r0 = rb + mi * 16;
#pragma unroll
      for (int r = 0; r < 4; ++r)
        C[(long)(r0 + r) * N_TOTAL + cb + nj * 16] = acc[mi][nj][r] + bv;
    }
}

extern "C" void kernel_launch(void* const* d_in, const int* in_sizes, int n_in,
                              void* d_out, int out_size, void* d_ws, size_t ws_size,
                              hipStream_t stream) {
  const float* x = (const float*)d_in[0];
  const float* W = (const float*)d_in[1];
  const float* bias = (const float*)d_in[2];
  float* out = (float*)d_out;

  short* xb = (short*)d_ws;                                          // 134 MB
  short* wh = (short*)((char*)d_ws + (size_t)M_TOTAL * K_TOTAL * 2); // 33.5 MB

  prep_kernel<<<4096, 256, 0, stream>>>(x, xb, W, wh);

  const int grid = (M_TOTAL / 256) * (N_TOTAL / 256); // 256
  gemm_kernel<<<grid, 512, 0, stream>>>(xb, wh, bias, out);
}

// Round 20
// 306.111 us; speedup vs baseline: 1.4630x; 1.0325x over previous
//
#include <hip/hip_runtime.h>
#include <hip/hip_bf16.h>
#include <stdint.h>

// out = x @ W'^T + bias, W' = FWHT(W rows)/sqrt(n)  (H symmetric, folded into W)
// x (4,2048,8192) f32 -> M=8192, K=8192 ; W (2048,8192) -> N=2048 ; out f32.
// R20: revert to R18 (proven 316us). In-gemm cvt family CLOSED after 3 failures
// (R16: "memory" clobber forced vmcnt(0); R17: FIFO position forced vmcnt(0);
// R19: asm/builtin issue-order not enforceable without a clobber -> race).
// Only change vs R18: prep at 512 threads (halves fwht's per-barrier-round
// work; cvt stride updated accordingly).

#define M_TOTAL 8192
#define K_TOTAL 8192
#define N_TOTAL 2048
#define D_IN 8192

typedef __attribute__((ext_vector_type(8))) short short8;
typedef __attribute__((ext_vector_type(4))) float f32x4;

typedef __attribute__((address_space(1))) void void_g;
typedef __attribute__((address_space(3))) void void_l;
typedef __attribute__((address_space(3))) short lds_s3;

__device__ __forceinline__ short f2bf(float f) {
  __hip_bfloat16 h = __float2bfloat16(f);
  return *reinterpret_cast<short*>(&h);
}

// ---------------- kernel 1: fused prep (cvt_x || fwht_w, parity-interleaved) ----
__global__ __launch_bounds__(512) void prep_kernel(const float* __restrict__ x,
                                                   short* __restrict__ xb,
                                                   const float* __restrict__ W,
                                                   short* __restrict__ wh) {
  __shared__ float buf[D_IN];
  const int b = blockIdx.x;
  if ((b & 1) == 0) {
    // ---- cvt path (blocks 0,2,...,8190 -> 2048 workers x 512 threads) ----
    const int cb = b >> 1;
    const long n = (long)M_TOTAL * K_TOTAL;
    const long stride = (long)2048 * 512 * 8;
    for (long i = ((long)cb * 512 + threadIdx.x) * 8; i < n; i += stride) {
      float4 v0 = *(const float4*)(x + i);
      float4 v1 = *(const float4*)(x + i + 4);
      short8 o;
      o[0] = f2bf(v0.x); o[1] = f2bf(v0.y); o[2] = f2bf(v0.z); o[3] = f2bf(v0.w);
      o[4] = f2bf(v1.x); o[5] = f2bf(v1.y); o[6] = f2bf(v1.z); o[7] = f2bf(v1.w);
      *(short8*)(xb + i) = o;
    }
  } else {
    // ---- fwht path (blocks 1,3,...,4095 -> 2048 rows) ----
    const int row = b >> 1;
    const float* src = W + (long)row * D_IN;
    for (int i = threadIdx.x; i < D_IN / 4; i += blockDim.x)
      ((float4*)buf)[i] = ((const float4*)src)[i];
    for (int h = 1; h < D_IN; h <<= 1) {
      __syncthreads();
      for (int p = threadIdx.x; p < D_IN / 2; p += blockDim.x) {
        int i = ((p & ~(h - 1)) << 1) | (p & (h - 1));
        float a = buf[i], bb = buf[i + h];
        buf[i] = a + bb;
        buf[i + h] = a - bb;
      }
    }
    __syncthreads();
    const float s = 0.011048543456039806f; // 1/sqrt(8192)
    short* dst = wh + (long)row * D_IN;
    for (int i = threadIdx.x; i < D_IN; i += blockDim.x)
      dst[i] = f2bf(buf[i] * s);
  }
}

// ---------------- kernel 2: 256x256 8-phase GEMM, coalesced XOR-swizzled LDS ----
// R14/R18 gemm, UNCHANGED (229 us, ~1200 TF, MfmaUtil 53%, 0 bank conflicts):
// 8-phase schedule (BK=64, 2-dbuf, per-phase barriers, vmcnt(4)/K-tile,
// lgkm(8) stagger) with coalesced staging. Halves = [128 rows][64 k] bf16
// row-major, 16B-chunk XOR swizzle: chunk c of row r stored at slot c ^ (r&7).
#define NT 128 // K-tiles of 64

#define ADST(D, H) (((D) * 2 + (H)) * 8192 + sdst)          // shorts
#define BDST(D, H) (32768 + ((D) * 2 + (H)) * 8192 + sdst)  // shorts

#define STG(DST, SRC, KOFF)                                                                       \
  __builtin_amdgcn_global_load_lds((void_g*)((SRC) + (KOFF)), (void_l*)&lds[DST], 16, 0, 0);      \
  __builtin_amdgcn_global_load_lds((void_g*)((SRC) + (KOFF) + 64 * (long)K_TOTAL),                \
                                   (void_l*)&lds[(DST) + 4096], 16, 0, 0);

#define DSR(dst, ADDR, IMM)                                                                       \
  asm volatile("ds_read_b128 %0, %1 offset:%2" : "=v"(dst) : "v"(ADDR), "i"(IMM))

#define RD_A4(D, MIB)                                                                             \
  DSR(am[0][0], aAd0, (D) * 32768 + ((MIB) + 0) * 2048);                                          \
  DSR(am[0][1], aAd1, (D) * 32768 + ((MIB) + 0) * 2048);                                          \
  DSR(am[1][0], aAd0, (D) * 32768 + ((MIB) + 1) * 2048);                                          \
  DSR(am[1][1], aAd1, (D) * 32768 + ((MIB) + 1) * 2048);                                          \
  DSR(am[2][0], aAd0, (D) * 32768 + ((MIB) + 2) * 2048);                                          \
  DSR(am[2][1], aAd1, (D) * 32768 + ((MIB) + 2) * 2048);                                          \
  DSR(am[3][0], aAd0, (D) * 32768 + ((MIB) + 3) * 2048);                                          \
  DSR(am[3][1], aAd1, (D) * 32768 + ((MIB) + 3) * 2048);

#define RD_B2(D, NJB)                                                                             \
  DSR(bn[(NJB) + 0][0], bAd0, (D) * 32768 + ((NJB) + 0) * 2048);                                  \
  DSR(bn[(NJB) + 0][1], bAd1, (D) * 32768 + ((NJB) + 0) * 2048);                                  \
  DSR(bn[(NJB) + 1][0], bAd0, (D) * 32768 + ((NJB) + 1) * 2048);                                  \
  DSR(bn[(NJB) + 1][1], bAd1, (D) * 32768 + ((NJB) + 1) * 2048);

#define MF(MIB, NJB)                                                                              \
  __builtin_amdgcn_s_setprio(1);                                                                  \
  _Pragma("unroll") for (int mi = 0; mi < 4; ++mi) {                                              \
    _Pragma("unroll") for (int nj = 0; nj < 2; ++nj) {                                            \
      _Pragma("unroll") for (int ks = 0; ks < 2; ++ks) acc[(MIB) + mi][(NJB) + nj] =              \
          __builtin_amdgcn_mfma_f32_16x16x32_bf16(am[mi][ks], bn[(NJB) + nj][ks],                 \
                                                  acc[(MIB) + mi][(NJB) + nj], 0, 0, 0);          \
    }                                                                                             \
  }                                                                                               \
  __builtin_amdgcn_s_setprio(0);

#define BAR __builtin_amdgcn_s_barrier()
#define SBAR __builtin_amdgcn_sched_barrier(0)
#define LG0 do { asm volatile("s_waitcnt lgkmcnt(0)"); SBAR; } while (0)

#define KTILE(D, STGA, KA, STGB, KB, FN, DOF, LB)                                                 \
  {                                                                                               \
    RD_B2(D, 0);                                                                                  \
    RD_A4(D, 0);                                                                                  \
    if (STGA) { STG(ADST(D ^ 1, 0), aSrc0, KA); }                                                 \
    asm volatile("s_waitcnt lgkmcnt(8)");                                                         \
    BAR;                                                                                          \
    LG0;                                                                                          \
    MF(0, 0);                                                                                     \
    BAR;                                                                                          \
    RD_B2(D, 2);                                                                                  \
    if (STGA) { STG(ADST(D ^ 1, 1), aSrc1, KA); }                                                 \
    BAR;                                                                                          \
    LG0;                                                                                          \
    MF(0, 2);                                                                                     \
    BAR;                                                                                          \
    RD_A4(D, 4);                                                                                  \
    if (STGB) { STG(BDST(D, 0), bSrc0, KB); }                                                     \
    BAR;                                                                                          \
    LG0;                                                                                          \
    MF(4, 0);                                                                                     \
    BAR;                                                                                          \
    if (STGB) { STG(BDST(D, 1), bSrc1, KB); }                                                     \
    BAR;                                                                                          \
    MF(4, 2);                                                                                     \
    if (DOF) { asm volatile("s_waitcnt vmcnt(" FN ")"); }                                         \
    if (LB) BAR;                                                                                  \
  }

__global__ __launch_bounds__(512, 2) void gemm_kernel(const short* __restrict__ A,
                                                      const short* __restrict__ B,
                                                      const float* __restrict__ bias,
                                                      float* __restrict__ C) {
  __shared__ __attribute__((aligned(16))) short lds[65536]; // 128 KiB

  const int tid = threadIdx.x;
  const int l = tid & 63;
  const int w = tid >> 6;
  const int wm = w >> 2;   // 0..1 (M half)
  const int wn = w & 3;    // 0..3 (N quarter)
  const int wh = wn >> 1;  // B half

  // XCD-aware bijective swizzle (nwg = 256)
  const int bid = blockIdx.x;
  const int swz = (bid & 7) * 32 + (bid >> 3);
  const int bm = swz >> 3;
  const int bn_ = swz & 7;
  const long tileM = (long)bm * 256;
  const long tileN = (long)bn_ * 256;

  // read bases (bytes): row-in-frag = l&15, slot0 = (l>>4) ^ (l&7); ks1 = ^64
  const int slot0 = (l >> 4) ^ (l & 7);
  const int laneb = (l & 15) * 128 + slot0 * 16;
  const unsigned ldsb = (unsigned)(uintptr_t)(lds_s3*)&lds[0];
  const unsigned aAd0 = ldsb + (unsigned)(wm * 16384 + laneb);
  const unsigned aAd1 = aAd0 ^ 64u;
  const unsigned bAd0 = ldsb + 65536u + (unsigned)(wh * 16384 + (wn & 1) * 8192 + laneb);
  const unsigned bAd1 = bAd0 ^ 64u;

  // staging: thread t -> LDS chunk t (row t>>3, slot t&7); global source chunk
  // (t&7)^((t>>3)&7) of row t>>3 (and +64 rows for the second load)
  const int sdst = tid * 8; // shorts
  const int srow = tid >> 3;
  const int sslot = ((tid & 7) ^ (srow & 7)) * 8; // shorts
  const short* aSrc0 = A + (tileM + srow) * (long)K_TOTAL + sslot;
  const short* aSrc1 = aSrc0 + 128 * (long)K_TOTAL;
  const short* bSrc0 = B + (tileN + srow) * (long)K_TOTAL + sslot;
  const short* bSrc1 = bSrc0 + 128 * (long)K_TOTAL;

  f32x4 acc[8][4];
#pragma unroll
  for (int mi = 0; mi < 8; ++mi)
#pragma unroll
    for (int nj = 0; nj < 4; ++nj)
      acc[mi][nj] = (f32x4){0.f, 0.f, 0.f, 0.f};

  // prologue: A(0)->d0, B(0)->d0, B(1)->d1 (12 loads); vmcnt(4) leaves B(1)
  STG(ADST(0, 0), aSrc0, 0);
  STG(ADST(0, 1), aSrc1, 0);
  STG(BDST(0, 0), bSrc0, 0);
  STG(BDST(0, 1), bSrc1, 0);
  STG(BDST(1, 0), bSrc0, 64);
  STG(BDST(1, 1), bSrc1, 64);
  asm volatile("s_waitcnt vmcnt(4)");
  BAR;

  short8 am[4][2], bn[4][2];

  // main: t = 0,2,...,124
  for (int t = 0; t < NT - 2; t += 2) {
    KTILE(0, true, (t + 1) * 64, true, (t + 2) * 64, "4", true, true);
    KTILE(1, true, (t + 2) * 64, true, (t + 3) * 64, "4", true, true);
  }
  // tail: t=126 stages A(127), drains; t=127 compute-only
  KTILE(0, true, 127 * 64, false, 0, "0", true, true);
  KTILE(1, false, 0, false, 0, "0", false, false);

  // epilogue: C = acc + bias  (C/D map: col = l&15, row = (l>>4)*4 + reg)
  const int rb = (int)tileM + wm * 128 + (l >> 4) * 4;
  const int cb = (int)tileN + wn * 64 + (l & 15);
#pragma unroll
  for (int mi = 0; mi < 8; ++mi)
#pragma unroll
    for (int nj = 0; nj < 4; ++nj) {
      float bv = bias[cb + nj * 16];
      const int r0 = rb + mi * 16;
#pragma unroll
      for (int r = 0; r < 4; ++r)
        C[(long)(r0 + r) * N_TOTAL + cb + nj * 16] = acc[mi][nj][r] + bv;
    }
}

extern "C" void kernel_launch(void* const* d_in, const int* in_sizes, int n_in,
                              void* d_out, int out_size, void* d_ws, size_t ws_size,
                              hipStream_t stream) {
  const float* x = (const float*)d_in[0];
  const float* W = (const float*)d_in[1];
  const float* bias = (const float*)d_in[2];
  float* out = (float*)d_out;

  short* xb = (short*)d_ws;                                          // 134 MB
  short* wh = (short*)((char*)d_ws + (size_t)M_TOTAL * K_TOTAL * 2); // 33.5 MB

  prep_kernel<<<4096, 512, 0, stream>>>(x, xb, W, wh);

  const int grid = (M_TOTAL / 256) * (N_TOTAL / 256); // 256
  gemm_kernel<<<grid, 512, 0, stream>>>(xb, wh, bias, out);
}